// Round 6
// baseline (1367.662 us; speedup 1.0000x reference)
//
#include <hip/hip_runtime.h>
#include <hip/hip_fp16.h>
#include <math.h>

// Problem constants (from reference file)
constexpr int N_NODES  = 50000;
constexpr int N_EDGES  = 1600000;
constexpr int G_GRAPHS = 64;
constexpr int D        = 32;
constexpr int D_ATTR   = 16;
constexpr int N_RBF    = 8;

// rw(len) lookup table: 8192 intervals over [0, LMAX], nearest-neighbor, fp16.
constexpr int   TBL      = 8192;
constexpr int   TBL_ROWS = TBL + 1;
constexpr float LMAX     = 10.0f;

// Tiled edge binning: dst-tiles of 64 nodes, 8 streams per tile (grp =
// scatter blockIdx & 7 ~ XCD). Stream expected count = 64*32/8 = 256,
// sigma ~ 16; CAP=512 is +16 sigma -> overflow probability ~ 0.
constexpr int NT     = 64;                       // nodes per tile
constexpr int NTILES = (N_NODES + NT - 1) / NT;  // 782
constexpr int NGRP   = 8;
constexpr int CAP    = 512;                      // records per stream

__device__ __forceinline__ float silu(float x) {
    return x / (1.0f + __expf(-x));
}

// ---------------------------------------------------------------------------
// 1) Node init: x_attr = W_elem[x], h = x_attr@W0 + b0, hm0 = h@Wmsg[0] (fp16)
// ---------------------------------------------------------------------------
__global__ void node_init_kernel(const int* __restrict__ x,
                                 const float* __restrict__ W_elem,
                                 const float* __restrict__ W0,
                                 const float* __restrict__ b0,
                                 const float* __restrict__ Wmsg0,
                                 float* __restrict__ x_attr,
                                 float* __restrict__ h,
                                 __half* __restrict__ hm) {
    int t = blockIdx.x * blockDim.x + threadIdx.x;
    int n = t >> 5, c = t & 31;
    if (n >= N_NODES) return;
    int sp = x[n];
    const float* we = W_elem + sp * D_ATTR;
    float acc = b0[c];
#pragma unroll
    for (int a = 0; a < D_ATTR; ++a) acc += we[a] * W0[a * D + c];
    h[n * D + c] = acc;
    if (c < D_ATTR) x_attr[n * D_ATTR + c] = we[c];
    float m = 0.0f;
#pragma unroll
    for (int j = 0; j < D; ++j) {
        float hj = __shfl(acc, j, 32);
        m = fmaf(hj, Wmsg0[j * D + c], m);
    }
    hm[n * D + c] = __float2half(m);
}

// ---------------------------------------------------------------------------
// 2) Edge geometry + tiled binning. Streams are written sequentially by
//    concurrent waves -> ~4 records share a 64B line (round 5's per-node
//    buckets gave 4x write amp: one line per record).
//    rec = { src | (tbl_idx<<16), dstLocal, half2(sw0,sw1), half(sw2) }
// ---------------------------------------------------------------------------
__global__ void scatter_kernel(const int* __restrict__ eidx,
                               const float* __restrict__ pos,
                               const float* __restrict__ period,
                               const float* __restrict__ wsh,
                               int* __restrict__ cursor,
                               uint4* __restrict__ rec) {
    int e = blockIdx.x * blockDim.x + threadIdx.x;
    if (e >= N_EDGES) return;
    int s = eidx[e];
    int d = eidx[N_EDGES + e];
    float vx = pos[d * 3 + 0] - pos[s * 3 + 0] + period[e * 3 + 0];
    float vy = pos[d * 3 + 1] - pos[s * 3 + 1] + period[e * 3 + 1];
    float vz = pos[d * 3 + 2] - pos[s * 3 + 2] + period[e * 3 + 2];
    float len = sqrtf(vx * vx + vy * vy + vz * vz);
    float inv = 1.0f / (len + 1e-9f);
    int idx = (int)fminf(len * ((float)TBL / LMAX) + 0.5f, (float)TBL);
    float sw[3];
#pragma unroll
    for (int l = 0; l < 3; ++l)
        sw[l] = wsh[l * 4 + 0] + (vx * wsh[l * 4 + 1] + vy * wsh[l * 4 + 2] + vz * wsh[l * 4 + 3]) * inv;

    int tile = d >> 6;         // d / NT
    int dl = d & (NT - 1);
    int stream = tile * NGRP + (blockIdx.x & (NGRP - 1));
    int slot = atomicAdd(&cursor[stream], 1);
    if (slot < CAP) {
        unsigned u0 = (unsigned)__half_as_ushort(__float2half(sw[0]));
        unsigned u1 = (unsigned)__half_as_ushort(__float2half(sw[1]));
        unsigned u2 = (unsigned)__half_as_ushort(__float2half(sw[2]));
        uint4 r;
        r.x = (unsigned)s | ((unsigned)idx << 16);
        r.y = (unsigned)dl;
        r.z = u0 | (u1 << 16);
        r.w = u2;
        rec[(size_t)stream * CAP + slot] = r;
    }
}

// ---------------------------------------------------------------------------
// 3) Build fp16 rw(len) tables for the 3 layers: table[l][idx][c]
// ---------------------------------------------------------------------------
__global__ void table_kernel(const float* __restrict__ Wr1,
                             const float* __restrict__ br1,
                             const float* __restrict__ Wr2,
                             __half* __restrict__ table) {
    int t = blockIdx.x * blockDim.x + threadIdx.x;
    if (t >= 3 * TBL_ROWS) return;
    int l = t / TBL_ROWS;
    int idx = t % TBL_ROWS;
    float len = (float)idx * (LMAX / (float)TBL);
    const float gamma = (8.0f / 5.0f) * (8.0f / 5.0f);  // (N_RBF/CUTOFF)^2
    float rbf[N_RBF];
#pragma unroll
    for (int k = 0; k < N_RBF; ++k) {
        float dd = len - (float)k * (5.0f / 7.0f);  // linspace(0, CUTOFF, 8)
        rbf[k] = __expf(-gamma * dd * dd);
    }
    float out[D];
#pragma unroll
    for (int c = 0; c < D; ++c) out[c] = 0.0f;
    for (int j = 0; j < D; ++j) {
        float z = br1[l * D + j];
#pragma unroll
        for (int k = 0; k < N_RBF; ++k) z += rbf[k] * Wr1[l * N_RBF * D + k * D + j];
        z = fmaxf(z, 0.0f);
        const float* w2 = Wr2 + l * D * D + j * D;
#pragma unroll
        for (int c = 0; c < D; ++c) out[c] += z * w2[c];
    }
    __half* dst = table + ((size_t)(l * TBL_ROWS + idx)) * D;
#pragma unroll
    for (int c = 0; c < D; ++c) dst[c] = __float2half(out[c]);
}

__device__ __forceinline__ float pick_sw(const uint4& r, int layer01_2) {
    // layer 0: low half of r.z; layer 1: high half of r.z; layer 2: low of r.w
    unsigned short us = (layer01_2 == 0) ? (unsigned short)(r.z & 0xFFFF)
                      : (layer01_2 == 1) ? (unsigned short)(r.z >> 16)
                                         : (unsigned short)(r.w & 0xFFFF);
    return __half2float(__ushort_as_half(us));
}

// ---------------------------------------------------------------------------
// 4) Conv layer: block-per-tile, LDS fp32 aggregation.
//    8 half-waves stream the tile's 8 bins (coalesced reads, x4 unroll = 32
//    edges in flight/block); per edge: tab/hm fp16 gathers (L2-hot) ->
//    atomicAdd into agg[64][32] LDS (lane=channel -> conflict-free).
//    Epilogue: fused node update (+ optional hm_next) for the 64 owned nodes.
// ---------------------------------------------------------------------------
template <int LAYER, bool WRITE_HM>
__global__ __launch_bounds__(256) void conv_kernel(const __half* __restrict__ hm,
                            const uint4* __restrict__ rec,
                            const int* __restrict__ cursor,
                            const float* __restrict__ x_attr,
                            const __half* __restrict__ table,
                            const float* __restrict__ Wattr,
                            const float* __restrict__ Wself,
                            const float* __restrict__ bconv,
                            const float* __restrict__ Wmsg_next,
                            float* __restrict__ h,
                            __half* __restrict__ hm_next) {
    __shared__ float agg[NT * D];  // 8 KB
    int tile = blockIdx.x;
    int tid = threadIdx.x;
    int halfId = tid >> 5;   // 0..7
    int c = tid & 31;

    for (int i = tid; i < NT * D; i += 256) agg[i] = 0.0f;
    __syncthreads();

    const __half* tab = table + ((size_t)LAYER * TBL_ROWS) * D;

    for (int grp = 0; grp < NGRP; ++grp) {
        int stream = tile * NGRP + grp;
        int cnt = cursor[stream];
        if (cnt > CAP) cnt = CAP;
        const uint4* base = rec + (size_t)stream * CAP;
        int k = halfId;
        for (; k + 24 < cnt; k += 32) {
            uint4 r0 = base[k];
            uint4 r1 = base[k + 8];
            uint4 r2 = base[k + 16];
            uint4 r3 = base[k + 24];
            int s0 = r0.x & 0xFFFF, i0 = r0.x >> 16, d0 = r0.y;
            int s1 = r1.x & 0xFFFF, i1 = r1.x >> 16, d1 = r1.y;
            int s2 = r2.x & 0xFFFF, i2 = r2.x >> 16, d2 = r2.y;
            int s3 = r3.x & 0xFFFF, i3 = r3.x >> 16, d3 = r3.y;
            float rw0 = __half2float(tab[i0 * D + c]);
            float rw1 = __half2float(tab[i1 * D + c]);
            float rw2 = __half2float(tab[i2 * D + c]);
            float rw3 = __half2float(tab[i3 * D + c]);
            float hv0 = __half2float(hm[s0 * D + c]);
            float hv1 = __half2float(hm[s1 * D + c]);
            float hv2 = __half2float(hm[s2 * D + c]);
            float hv3 = __half2float(hm[s3 * D + c]);
            atomicAdd(&agg[d0 * D + c], hv0 * rw0 * pick_sw(r0, LAYER));
            atomicAdd(&agg[d1 * D + c], hv1 * rw1 * pick_sw(r1, LAYER));
            atomicAdd(&agg[d2 * D + c], hv2 * rw2 * pick_sw(r2, LAYER));
            atomicAdd(&agg[d3 * D + c], hv3 * rw3 * pick_sw(r3, LAYER));
        }
        for (; k < cnt; k += 8) {
            uint4 r = base[k];
            int s = r.x & 0xFFFF, i = r.x >> 16, dl = r.y;
            float v = __half2float(hm[s * D + c]) * __half2float(tab[i * D + c]) * pick_sw(r, LAYER);
            atomicAdd(&agg[dl * D + c], v);
        }
    }
    __syncthreads();

    // Epilogue: each half-wave owns 8 consecutive nodes.
    const float* Ws = Wself + LAYER * D * D;
    const float* Wa = Wattr + LAYER * D_ATTR * D;
    float bc = bconv[LAYER * D + c];
#pragma unroll
    for (int i = 0; i < 8; ++i) {
        int nl = halfId * 8 + i;
        int node = tile * NT + nl;
        if (node >= N_NODES) break;
        float hload = h[node * D + c];
        float xload = (c < D_ATTR) ? x_attr[node * D_ATTR + c] : 0.0f;
        float pre = agg[nl * D + c] + bc;
#pragma unroll
        for (int j = 0; j < D; ++j) pre = fmaf(__shfl(hload, j, 32), Ws[j * D + c], pre);
#pragma unroll
        for (int j = 0; j < D_ATTR; ++j) pre = fmaf(__shfl(xload, j, 32), Wa[j * D + c], pre);
        float hn = silu(pre);
        h[node * D + c] = hn;
        if (WRITE_HM) {
            float m = 0.0f;
#pragma unroll
            for (int j = 0; j < D; ++j) m = fmaf(__shfl(hn, j, 32), Wmsg_next[j * D + c], m);
            hm_next[node * D + c] = __float2half(m);
        }
    }
}

// ---------------------------------------------------------------------------
// 5) Readout: per-node MLP scalar, wave-aggregated segment-sum (batch sorted
//    -> nearly all waves uniform: ~1 atomic per wave, not per node).
// ---------------------------------------------------------------------------
__global__ void readout_kernel(const float* __restrict__ h,
                               const int* __restrict__ batch,
                               const float* __restrict__ Wp1,
                               const float* __restrict__ bp1,
                               const float* __restrict__ Wp2,
                               const float* __restrict__ bp2,
                               float* __restrict__ out) {
    int n = blockIdx.x * blockDim.x + threadIdx.x;
    float s = 0.0f;
    int b = -1;
    if (n < N_NODES) {
        b = batch[n];
        const float* hrow = h + n * D;
        float acc2 = bp2[0];
#pragma unroll
        for (int m = 0; m < 16; ++m) {
            float a = bp1[m];
#pragma unroll
            for (int j = 0; j < D; ++j) a += hrow[j] * Wp1[j * 16 + m];
            acc2 += silu(a) * Wp2[m];
        }
        s = acc2;  // SCALE=1, SHIFT=0 baked in
    }
    unsigned long long valid = __ballot(n < N_NODES);
    if (valid == 0ull) return;
    int firstLane = __ffsll(valid) - 1;
    int b0v = __shfl(b, firstLane);
    bool ok = (b == b0v) || (n >= N_NODES);
    if (__all(ok)) {
#pragma unroll
        for (int o = 32; o > 0; o >>= 1) s += __shfl_down(s, o);
        if ((threadIdx.x & 63) == 0) atomicAdd(out + b0v, s);
    } else {
        if (n < N_NODES) atomicAdd(out + b, s);
    }
}

// ---------------------------------------------------------------------------
extern "C" void kernel_launch(void* const* d_in, const int* in_sizes, int n_in,
                              void* d_out, int out_size, void* d_ws, size_t ws_size,
                              hipStream_t stream) {
    const int*   x      = (const int*)d_in[0];
    const float* pos    = (const float*)d_in[1];
    const int*   eidx   = (const int*)d_in[2];
    const float* period = (const float*)d_in[3];
    const int*   batch  = (const int*)d_in[4];
    const float* W_elem = (const float*)d_in[5];
    const float* W0     = (const float*)d_in[6];
    const float* b0     = (const float*)d_in[7];
    const float* Wr1    = (const float*)d_in[8];
    const float* br1    = (const float*)d_in[9];
    const float* Wr2    = (const float*)d_in[10];
    const float* Wmsg   = (const float*)d_in[11];
    const float* Wattr  = (const float*)d_in[12];
    const float* Wself  = (const float*)d_in[13];
    const float* bconv  = (const float*)d_in[14];
    const float* wsh    = (const float*)d_in[15];
    const float* Wp1    = (const float*)d_in[16];
    const float* bp1    = (const float*)d_in[17];
    const float* Wp2    = (const float*)d_in[18];
    const float* bp2    = (const float*)d_in[19];

    char* base = (char*)d_ws;
    size_t off = 0;
    auto carve = [&](size_t bytes) -> void* {
        void* p = base + off;
        off = (off + bytes + 255) & ~(size_t)255;
        return p;
    };
    float*  x_attr = (float*)carve((size_t)N_NODES * D_ATTR * 4);
    float*  h      = (float*)carve((size_t)N_NODES * D * 4);
    __half* hm_a   = (__half*)carve((size_t)N_NODES * D * 2);
    __half* hm_b   = (__half*)carve((size_t)N_NODES * D * 2);
    uint4*  rec    = (uint4*)carve((size_t)NTILES * NGRP * CAP * 16);
    int*    cursor = (int*)carve((size_t)NTILES * NGRP * 4);
    __half* table  = (__half*)carve((size_t)3 * TBL_ROWS * D * 2);
    (void)ws_size; (void)in_sizes; (void)n_in; (void)out_size;

    hipMemsetAsync(cursor, 0, (size_t)NTILES * NGRP * 4, stream);
    hipMemsetAsync(d_out, 0, (size_t)G_GRAPHS * 4, stream);

    node_init_kernel<<<(N_NODES * 32 + 255) / 256, 256, 0, stream>>>(
        x, W_elem, W0, b0, Wmsg + 0 * D * D, x_attr, h, hm_a);
    scatter_kernel<<<(N_EDGES + 255) / 256, 256, 0, stream>>>(eidx, pos, period, wsh, cursor, rec);
    table_kernel<<<(3 * TBL_ROWS + 127) / 128, 128, 0, stream>>>(Wr1, br1, Wr2, table);

    conv_kernel<0, true><<<NTILES, 256, 0, stream>>>(
        hm_a, rec, cursor, x_attr, table, Wattr, Wself, bconv, Wmsg + 1 * D * D, h, hm_b);
    conv_kernel<1, true><<<NTILES, 256, 0, stream>>>(
        hm_b, rec, cursor, x_attr, table, Wattr, Wself, bconv, Wmsg + 2 * D * D, h, hm_a);
    conv_kernel<2, false><<<NTILES, 256, 0, stream>>>(
        hm_a, rec, cursor, x_attr, table, Wattr, Wself, bconv, nullptr, h, nullptr);

    readout_kernel<<<(N_NODES + 255) / 256, 256, 0, stream>>>(h, batch, Wp1, bp1, Wp2, bp2,
                                                              (float*)d_out);
}

// Round 7
// 417.664 us; speedup vs baseline: 3.2745x; 3.2745x over previous
//
#include <hip/hip_runtime.h>
#include <hip/hip_fp16.h>
#include <math.h>

// Problem constants (from reference file)
constexpr int N_NODES  = 50000;
constexpr int N_EDGES  = 1600000;
constexpr int G_GRAPHS = 64;
constexpr int D        = 32;
constexpr int D_ATTR   = 16;
constexpr int N_RBF    = 8;

// rw(len) lookup table: 8192 intervals over [0, LMAX], nearest-neighbor, fp16.
constexpr int   TBL      = 8192;
constexpr int   TBL_ROWS = TBL + 1;
constexpr float LMAX     = 10.0f;

// Fixed-stride per-node edge buckets. deg ~ Poisson(32): P(deg > 80) ~ 1e-11.
constexpr int BUCKET = 80;

__device__ __forceinline__ float silu(float x) {
    return x / (1.0f + __expf(-x));
}

// ---------------------------------------------------------------------------
// 1) Node init: x_attr = W_elem[x], h = x_attr@W0 + b0, hm0 = h@Wmsg[0] (fp16),
//    cursor[n] = n*BUCKET.  32 threads/node.
// ---------------------------------------------------------------------------
__global__ void node_init_kernel(const int* __restrict__ x,
                                 const float* __restrict__ W_elem,
                                 const float* __restrict__ W0,
                                 const float* __restrict__ b0,
                                 const float* __restrict__ Wmsg0,
                                 float* __restrict__ x_attr,
                                 float* __restrict__ h,
                                 __half* __restrict__ hm,
                                 int* __restrict__ cursor) {
    int t = blockIdx.x * blockDim.x + threadIdx.x;
    int n = t >> 5, c = t & 31;
    if (n >= N_NODES) return;
    int sp = x[n];
    const float* we = W_elem + sp * D_ATTR;
    float acc = b0[c];
#pragma unroll
    for (int a = 0; a < D_ATTR; ++a) acc += we[a] * W0[a * D + c];
    h[n * D + c] = acc;
    if (c < D_ATTR) x_attr[n * D_ATTR + c] = we[c];
    if (c == 0) cursor[n] = n * BUCKET;
    float m = 0.0f;
#pragma unroll
    for (int j = 0; j < D; ++j) {
        float hj = __shfl(acc, j, 32);
        m = fmaf(hj, Wmsg0[j * D + c], m);
    }
    hm[n * D + c] = __float2half(m);
}

// ---------------------------------------------------------------------------
// 2) Edge geometry + bucket scatter (identical to round 5: known 105 us,
//    scatter-write-line-bound; VALU is free here).
//    rec[k] = { __int_as_float(src | (tbl_idx<<16)), sw_l0, sw_l1, sw_l2 }
// ---------------------------------------------------------------------------
__global__ void scatter_kernel(const int* __restrict__ eidx,
                               const float* __restrict__ pos,
                               const float* __restrict__ period,
                               const float* __restrict__ wsh,
                               int* __restrict__ cursor,
                               float4* __restrict__ rec) {
    int e = blockIdx.x * blockDim.x + threadIdx.x;
    if (e >= N_EDGES) return;
    int s = eidx[e];
    int d = eidx[N_EDGES + e];
    float vx = pos[d * 3 + 0] - pos[s * 3 + 0] + period[e * 3 + 0];
    float vy = pos[d * 3 + 1] - pos[s * 3 + 1] + period[e * 3 + 1];
    float vz = pos[d * 3 + 2] - pos[s * 3 + 2] + period[e * 3 + 2];
    float len = sqrtf(vx * vx + vy * vy + vz * vz);
    float inv = 1.0f / (len + 1e-9f);
    int idx = (int)fminf(len * ((float)TBL / LMAX) + 0.5f, (float)TBL);
    float sw[3];
#pragma unroll
    for (int l = 0; l < 3; ++l)
        sw[l] = wsh[l * 4 + 0] + (vx * wsh[l * 4 + 1] + vy * wsh[l * 4 + 2] + vz * wsh[l * 4 + 3]) * inv;
    int k = atomicAdd(&cursor[d], 1);
    if (k < d * BUCKET + BUCKET)  // hard clamp (P ~ 1e-11)
        rec[k] = make_float4(__int_as_float(s | (idx << 16)), sw[0], sw[1], sw[2]);
}

// ---------------------------------------------------------------------------
// 3) Build fp16 rw(len) tables for the 3 layers: table[l][idx][c]
// ---------------------------------------------------------------------------
__global__ void table_kernel(const float* __restrict__ Wr1,
                             const float* __restrict__ br1,
                             const float* __restrict__ Wr2,
                             __half* __restrict__ table) {
    int t = blockIdx.x * blockDim.x + threadIdx.x;
    if (t >= 3 * TBL_ROWS) return;
    int l = t / TBL_ROWS;
    int idx = t % TBL_ROWS;
    float len = (float)idx * (LMAX / (float)TBL);
    const float gamma = (8.0f / 5.0f) * (8.0f / 5.0f);  // (N_RBF/CUTOFF)^2
    float rbf[N_RBF];
#pragma unroll
    for (int k = 0; k < N_RBF; ++k) {
        float dd = len - (float)k * (5.0f / 7.0f);  // linspace(0, CUTOFF, 8)
        rbf[k] = __expf(-gamma * dd * dd);
    }
    float out[D];
#pragma unroll
    for (int c = 0; c < D; ++c) out[c] = 0.0f;
    for (int j = 0; j < D; ++j) {
        float z = br1[l * D + j];
#pragma unroll
        for (int k = 0; k < N_RBF; ++k) z += rbf[k] * Wr1[l * N_RBF * D + k * D + j];
        z = fmaxf(z, 0.0f);
        const float* w2 = Wr2 + l * D * D + j * D;
#pragma unroll
        for (int c = 0; c < D; ++c) out[c] += z * w2[c];
    }
    __half* dst = table + ((size_t)(l * TBL_ROWS + idx)) * D;
#pragma unroll
    for (int c = 0; c < D; ++c) dst[c] = __float2half(out[c]);
}

// ---------------------------------------------------------------------------
// 4) Conv layer: wave-per-node, QUARTER-WAVE per edge, half2 channel pairs.
//    lane = {qw(2b), q(4b)}: quarter qw handles bucket slots beg+qw, +4, ...;
//    lane q covers channels {2q, 2q+1} via __half2 gathers (full 64B lines).
//    One wave processes 4 edges per instruction (vs 2 in round 5) -> halves
//    per-edge VALU + memory-instruction count. Unroll x4 = 16 edges in
//    flight/wave. fp32 accumulate; shfl_xor reduce; round-5 fused epilogue.
// ---------------------------------------------------------------------------
template <int LAYER, bool WRITE_HM>
__global__ void conv_kernel(const __half* __restrict__ hm,
                            const float4* __restrict__ rec,
                            const int* __restrict__ cursor,
                            const float* __restrict__ x_attr,
                            const __half* __restrict__ table,
                            const float* __restrict__ Wattr,
                            const float* __restrict__ Wself,
                            const float* __restrict__ bconv,
                            const float* __restrict__ Wmsg_next,
                            float* __restrict__ h,
                            __half* __restrict__ hm_next) {
    int gtid = blockIdx.x * blockDim.x + threadIdx.x;
    int node = gtid >> 6;
    if (node >= N_NODES) return;
    int lane = threadIdx.x & 63;
    int qw = lane >> 4;   // quarter id 0..3
    int q  = lane & 15;   // channel-pair id: channels {2q, 2q+1}

    const __half2* tab2 = (const __half2*)(table + ((size_t)LAYER * TBL_ROWS) * D);
    const __half2* hm2  = (const __half2*)hm;
    int beg = node * BUCKET;
    int end = cursor[node];
    if (end > beg + BUCKET) end = beg + BUCKET;

    float ax0 = 0.f, ay0 = 0.f, ax1 = 0.f, ay1 = 0.f;
    float ax2 = 0.f, ay2 = 0.f, ax3 = 0.f, ay3 = 0.f;
    int k = beg + qw;
    for (; k + 12 < end; k += 16) {
        float4 r0 = rec[k];
        float4 r1 = rec[k + 4];
        float4 r2 = rec[k + 8];
        float4 r3 = rec[k + 12];
        int p0 = __float_as_int(r0.x), p1 = __float_as_int(r1.x);
        int p2 = __float_as_int(r2.x), p3 = __float_as_int(r3.x);
        int s0 = p0 & 0xFFFF, s1 = p1 & 0xFFFF, s2 = p2 & 0xFFFF, s3 = p3 & 0xFFFF;
        int i0 = (unsigned)p0 >> 16, i1 = (unsigned)p1 >> 16;
        int i2 = (unsigned)p2 >> 16, i3 = (unsigned)p3 >> 16;
        __half2 t0 = tab2[i0 * 16 + q];
        __half2 t1 = tab2[i1 * 16 + q];
        __half2 t2 = tab2[i2 * 16 + q];
        __half2 t3 = tab2[i3 * 16 + q];
        __half2 m0 = hm2[s0 * 16 + q];
        __half2 m1 = hm2[s1 * 16 + q];
        __half2 m2 = hm2[s2 * 16 + q];
        __half2 m3 = hm2[s3 * 16 + q];
        float sw0 = (LAYER == 0) ? r0.y : (LAYER == 1) ? r0.z : r0.w;
        float sw1 = (LAYER == 0) ? r1.y : (LAYER == 1) ? r1.z : r1.w;
        float sw2 = (LAYER == 0) ? r2.y : (LAYER == 1) ? r2.z : r2.w;
        float sw3 = (LAYER == 0) ? r3.y : (LAYER == 1) ? r3.z : r3.w;
        float2 tf0 = __half22float2(t0), mf0 = __half22float2(m0);
        float2 tf1 = __half22float2(t1), mf1 = __half22float2(m1);
        float2 tf2 = __half22float2(t2), mf2 = __half22float2(m2);
        float2 tf3 = __half22float2(t3), mf3 = __half22float2(m3);
        ax0 = fmaf(tf0.x * mf0.x, sw0, ax0);
        ay0 = fmaf(tf0.y * mf0.y, sw0, ay0);
        ax1 = fmaf(tf1.x * mf1.x, sw1, ax1);
        ay1 = fmaf(tf1.y * mf1.y, sw1, ay1);
        ax2 = fmaf(tf2.x * mf2.x, sw2, ax2);
        ay2 = fmaf(tf2.y * mf2.y, sw2, ay2);
        ax3 = fmaf(tf3.x * mf3.x, sw3, ax3);
        ay3 = fmaf(tf3.y * mf3.y, sw3, ay3);
    }
    for (; k < end; k += 4) {
        float4 r = rec[k];
        int p = __float_as_int(r.x);
        int s = p & 0xFFFF, i = (unsigned)p >> 16;
        float sw = (LAYER == 0) ? r.y : (LAYER == 1) ? r.z : r.w;
        float2 tf = __half22float2(tab2[i * 16 + q]);
        float2 mf = __half22float2(hm2[s * 16 + q]);
        ax0 = fmaf(tf.x * mf.x, sw, ax0);
        ay0 = fmaf(tf.y * mf.y, sw, ay0);
    }
    float ax = (ax0 + ax1) + (ax2 + ax3);
    float ay = (ay0 + ay1) + (ay2 + ay3);
    // reduce across the 4 quarters (lanes q, q+16, q+32, q+48)
    ax += __shfl_xor(ax, 16);
    ax += __shfl_xor(ax, 32);
    ay += __shfl_xor(ay, 16);
    ay += __shfl_xor(ay, 32);

    // redistribute to 32-lane channel layout: lane c needs pair c>>1, elem c&1
    int c = lane & 31;
    float vx = __shfl(ax, c >> 1);
    float vy = __shfl(ay, c >> 1);
    float agg = (c & 1) ? vy : vx;

    if ((lane >> 5) == 0) {
        float hload = h[node * D + c];
        float xload = (c < D_ATTR) ? x_attr[node * D_ATTR + c] : 0.0f;
        float pre = agg + bconv[LAYER * D + c];
        const float* Ws = Wself + LAYER * D * D;
        const float* Wa = Wattr + LAYER * D_ATTR * D;
#pragma unroll
        for (int j = 0; j < D; ++j) pre = fmaf(__shfl(hload, j), Ws[j * D + c], pre);
#pragma unroll
        for (int j = 0; j < D_ATTR; ++j) pre = fmaf(__shfl(xload, j), Wa[j * D + c], pre);
        float hn = silu(pre);
        h[node * D + c] = hn;
        if (WRITE_HM) {
            float m = 0.0f;
#pragma unroll
            for (int j = 0; j < D; ++j) m = fmaf(__shfl(hn, j), Wmsg_next[j * D + c], m);
            hm_next[node * D + c] = __float2half(m);
        }
    }
}

// ---------------------------------------------------------------------------
// 5) Readout: per-node MLP scalar, wave-aggregated segment-sum (batch sorted
//    -> nearly all waves uniform: ~1 atomic per wave).
// ---------------------------------------------------------------------------
__global__ void readout_kernel(const float* __restrict__ h,
                               const int* __restrict__ batch,
                               const float* __restrict__ Wp1,
                               const float* __restrict__ bp1,
                               const float* __restrict__ Wp2,
                               const float* __restrict__ bp2,
                               float* __restrict__ out) {
    int n = blockIdx.x * blockDim.x + threadIdx.x;
    float s = 0.0f;
    int b = -1;
    if (n < N_NODES) {
        b = batch[n];
        const float* hrow = h + n * D;
        float acc2 = bp2[0];
#pragma unroll
        for (int m = 0; m < 16; ++m) {
            float a = bp1[m];
#pragma unroll
            for (int j = 0; j < D; ++j) a += hrow[j] * Wp1[j * 16 + m];
            acc2 += silu(a) * Wp2[m];
        }
        s = acc2;  // SCALE=1, SHIFT=0 baked in
    }
    unsigned long long valid = __ballot(n < N_NODES);
    if (valid == 0ull) return;
    int firstLane = __ffsll(valid) - 1;
    int b0v = __shfl(b, firstLane);
    bool ok = (b == b0v) || (n >= N_NODES);
    if (__all(ok)) {
#pragma unroll
        for (int o = 32; o > 0; o >>= 1) s += __shfl_down(s, o);
        if ((threadIdx.x & 63) == 0) atomicAdd(out + b0v, s);
    } else {
        if (n < N_NODES) atomicAdd(out + b, s);
    }
}

// ---------------------------------------------------------------------------
extern "C" void kernel_launch(void* const* d_in, const int* in_sizes, int n_in,
                              void* d_out, int out_size, void* d_ws, size_t ws_size,
                              hipStream_t stream) {
    const int*   x      = (const int*)d_in[0];
    const float* pos    = (const float*)d_in[1];
    const int*   eidx   = (const int*)d_in[2];
    const float* period = (const float*)d_in[3];
    const int*   batch  = (const int*)d_in[4];
    const float* W_elem = (const float*)d_in[5];
    const float* W0     = (const float*)d_in[6];
    const float* b0     = (const float*)d_in[7];
    const float* Wr1    = (const float*)d_in[8];
    const float* br1    = (const float*)d_in[9];
    const float* Wr2    = (const float*)d_in[10];
    const float* Wmsg   = (const float*)d_in[11];
    const float* Wattr  = (const float*)d_in[12];
    const float* Wself  = (const float*)d_in[13];
    const float* bconv  = (const float*)d_in[14];
    const float* wsh    = (const float*)d_in[15];
    const float* Wp1    = (const float*)d_in[16];
    const float* bp1    = (const float*)d_in[17];
    const float* Wp2    = (const float*)d_in[18];
    const float* bp2    = (const float*)d_in[19];

    char* base = (char*)d_ws;
    size_t off = 0;
    auto carve = [&](size_t bytes) -> void* {
        void* p = base + off;
        off = (off + bytes + 255) & ~(size_t)255;
        return p;
    };
    float*  x_attr = (float*)carve((size_t)N_NODES * D_ATTR * 4);
    float*  h      = (float*)carve((size_t)N_NODES * D * 4);
    __half* hm_a   = (__half*)carve((size_t)N_NODES * D * 2);
    __half* hm_b   = (__half*)carve((size_t)N_NODES * D * 2);
    float4* rec    = (float4*)carve((size_t)N_NODES * BUCKET * 16);
    int*    cursor = (int*)carve((size_t)N_NODES * 4);
    __half* table  = (__half*)carve((size_t)3 * TBL_ROWS * D * 2);
    (void)ws_size; (void)in_sizes; (void)n_in; (void)out_size;

    hipMemsetAsync(d_out, 0, (size_t)G_GRAPHS * 4, stream);

    node_init_kernel<<<(N_NODES * 32 + 255) / 256, 256, 0, stream>>>(
        x, W_elem, W0, b0, Wmsg + 0 * D * D, x_attr, h, hm_a, cursor);
    scatter_kernel<<<(N_EDGES + 255) / 256, 256, 0, stream>>>(eidx, pos, period, wsh, cursor, rec);
    table_kernel<<<(3 * TBL_ROWS + 127) / 128, 128, 0, stream>>>(Wr1, br1, Wr2, table);

    int cgrid = (N_NODES * 64 + 255) / 256;
    conv_kernel<0, true><<<cgrid, 256, 0, stream>>>(
        hm_a, rec, cursor, x_attr, table, Wattr, Wself, bconv, Wmsg + 1 * D * D, h, hm_b);
    conv_kernel<1, true><<<cgrid, 256, 0, stream>>>(
        hm_b, rec, cursor, x_attr, table, Wattr, Wself, bconv, Wmsg + 2 * D * D, h, hm_a);
    conv_kernel<2, false><<<cgrid, 256, 0, stream>>>(
        hm_a, rec, cursor, x_attr, table, Wattr, Wself, bconv, nullptr, h, nullptr);

    readout_kernel<<<(N_NODES + 255) / 256, 256, 0, stream>>>(h, batch, Wp1, bp1, Wp2, bp2,
                                                              (float*)d_out);
}